// Round 12
// baseline (135.928 us; speedup 1.0000x reference)
//
#include <hip/hip_runtime.h>

// Forecaster: B=64, S=1024, F=64, H=128. N = B*S = 65536 independent instances.
// R21: asm-forced counted-vmcnt weight pipeline (T4, m218). R20 null killed
// the convoy theory; elimination table: occupancy/depth/residency/volume/
// phase all null. BUT R16's "2-deep null" never tested the hypothesis —
// the compiler serialized the HIP-source ring (VGPR +4, not +32). This
// round forces it at asm level:
//  - all weight (and bias) loads: inline-asm global_load_dwordx4 with SGPR
//    base + 32b voffset; 2-slot ring sA/sB issued 2 kc-steps ahead, across
//    stage boundaries and epilogues (loads ride lgkm-only barriers).
//  - literal s_waitcnt vmcnt(4) per kc (vmcnt(0) only at the very last kc),
//    awaited regs tied via "+v" so MFMAs can't hoist (rule #18) without
//    order-pinning sched_barriers (m141).
//  - issue order per stage X: [kc2: mfma; load bias_Y; issue Y.k0]
//    [kc3: wait(4)=X.k3+bias_Y done,Y.k0 in flight; mfma; issue Y.k1] ->
//    stage Y entry has Y.k1 + nothing stale in flight; Y.kc0 wait(4)
//    retires Y.k0. Ledger verified per-step in comments below.
//  - uniform 4-gate loads (f-gate loaded, MFMA skipped) keeps counts
//    literal-4.
// Kept: R19 sigtanh fusion + f-gate MFMA skip; R15 geometry (grid 1024,
// 64-row wgs); lgkm-only barriers; bias-as-MFMA-C; A0 aliases H2s (LDS
// 49152); swizzled H tiles; setprio; plain __launch_bounds__(512).
// ABORT criteria: VGPR>128 (occupancy cliff) or WRITE_SIZE>3MB (spill).
// NEVER: min-waves clamp (R12/R17).

typedef _Float16 half8 __attribute__((ext_vector_type(8)));
typedef _Float16 half4_t __attribute__((ext_vector_type(4)));
typedef float f32x4 __attribute__((ext_vector_type(4)));

#define L2E  1.4426950408889634f
#define L2E2 2.8853900817779268f

#define WP_WIH0 0
#define WP_WHH0 32768
#define WP_WIH1 98304
#define WP_WHH1 163840
#define WS_BIAS0 458752            // bytes
#define WS_BIAS1 (458752 + 2048)
#define WS_MUG2  (458752 + 4096)

// ---------------- merged prep kernel (unchanged) ----------------------------
__global__ void prep_kernel(const float* __restrict__ Wih0,
                            const float* __restrict__ Whh0,
                            const float* __restrict__ Wih1,
                            const float* __restrict__ Whh1,
                            const float* __restrict__ bih0,
                            const float* __restrict__ bhh0,
                            const float* __restrict__ bih1,
                            const float* __restrict__ bhh1,
                            const float* __restrict__ mu,
                            _Float16* __restrict__ Wp,
                            float* __restrict__ bias0f,
                            float* __restrict__ bias1f,
                            float* __restrict__ mu_g2)
{
    int blk = blockIdx.x;
    if (blk >= 113) {                       // ---- mu_g2 part
        int o = (blk - 113) * 256 + threadIdx.x;   // 0..32767
        int b = o >> 9;
        int n = o & 511;
        float s = bih0[n] + bhh0[n];
        const float* m = mu + b * 64;
        const float* wrow = Wih0 + n * 64;
        #pragma unroll 8
        for (int k = 0; k < 64; ++k) s += m[k] * wrow[k];
        float scale = ((n >> 7) == 2) ? L2E2 : L2E;
        mu_g2[o] = s * scale;
        return;
    }
    if (blk == 112) {                       // ---- bias part
        int i = threadIdx.x;
        float sc_hi = (i < 128) ? L2E2 : L2E;
        bias0f[i]       = (bih0[i]       + bhh0[i])       * L2E;
        bias0f[i + 256] = (bih0[i + 256] + bhh0[i + 256]) * sc_hi;
        bias1f[i]       = (bih1[i]       + bhh1[i])       * L2E;
        bias1f[i + 256] = (bih1[i + 256] + bhh1[i + 256]) * sc_hi;
        return;
    }
    // ---- weight pack: [nt][kc][lane][8], c=lane&15 -> n=nt*16+c,
    //      q=lane>>4 -> k = kc*32 + q*8 .. +8  (scaled by gate)
    int gidx = blk * 256 + threadIdx.x;     // 0..28671 groups of 8 halfs
    const float* src; int KC, Kw, local;
    if (gidx < 4096)       { src = Wih0; KC = 2; Kw = 64;  local = gidx; }
    else if (gidx < 12288) { src = Whh0; KC = 4; Kw = 128; local = gidx - 4096; }
    else if (gidx < 20480) { src = Wih1; KC = 4; Kw = 128; local = gidx - 12288; }
    else                   { src = Whh1; KC = 4; Kw = 128; local = gidx - 20480; }
    int lane = local & 63;
    int tmp  = local >> 6;
    int kc   = tmp % KC;
    int nt   = tmp / KC;
    int n  = nt * 16 + (lane & 15);
    int k0 = kc * 32 + (lane >> 4) * 8;
    float scale = ((n >> 7) == 2) ? L2E2 : L2E;
    const float* s = src + n * Kw + k0;
    half8 hv;
    #pragma unroll
    for (int j = 0; j < 8; ++j) hv[j] = (_Float16)(s[j] * scale);
    *(half8*)(Wp + (size_t)gidx * 8) = hv;
}

// ---------------- bare-metal gate math -------------------------------------
__device__ __forceinline__ float sig2(float a) {
    return __builtin_amdgcn_rcpf(1.0f + __builtin_amdgcn_exp2f(-a));
}
// Fused sig(x̂)·tanh(ŷ): 3 trans instead of 4 (R19).
__device__ __forceinline__ float sigtanh(float xs, float yt) {
    float d = __builtin_amdgcn_exp2f(-xs);
    float e = __builtin_amdgcn_exp2f(yt);
    return (e - 1.0f) * __builtin_amdgcn_rcpf((1.0f + d) * (1.0f + e));
}

// Swizzled byte offset into a [64 rows][256B] H tile (involution).
__device__ __forceinline__ int swz(int row, int col) {
    return (row << 8) + (col ^ ((row & 7) << 4));
}

// lgkm-only barrier: does NOT drain vmcnt — asm weight loads ride across.
__device__ __forceinline__ void lds_barrier() {
    asm volatile("s_waitcnt lgkmcnt(0)" ::: "memory");
    __builtin_amdgcn_s_barrier();
    asm volatile("" ::: "memory");
}

// ---------------- asm load / wait primitives --------------------------------
template<int OFF>
__device__ __forceinline__ void gload(half8 &d, unsigned vo, const _Float16* sbase) {
    asm volatile("global_load_dwordx4 %0, %1, %2 offset:%c3"
                 : "=v"(d) : "v"(vo), "s"(sbase), "n"(OFF));
}
template<int OFF>
__device__ __forceinline__ void gloadf(f32x4 &d, unsigned vo, const float* sbase) {
    asm volatile("global_load_dwordx4 %0, %1, %2 offset:%c3"
                 : "=v"(d) : "v"(vo), "s"(sbase), "n"(OFF));
}
// Counted waits; awaited regs tied so dependent MFMAs cannot hoist (rule #18).
#define WAIT4(s) \
    asm volatile("s_waitcnt vmcnt(4)" : "+v"((s)[0]), "+v"((s)[1]), "+v"((s)[2]), "+v"((s)[3]))
#define WAIT4B(s, b) \
    asm volatile("s_waitcnt vmcnt(4)" : "+v"((s)[0]), "+v"((s)[1]), "+v"((s)[2]), "+v"((s)[3]), \
                                        "+v"((b)[0]), "+v"((b)[1]), "+v"((b)[2]), "+v"((b)[3]))
#define WAIT0(s) \
    asm volatile("s_waitcnt vmcnt(0)" : "+v"((s)[0]), "+v"((s)[1]), "+v"((s)[2]), "+v"((s)[3]))

template<int OFF>
__device__ __forceinline__ void issue4(half8 s[4], const unsigned vo[4],
                                       const _Float16* base) {
    gload<OFF>(s[0], vo[0], base);
    gload<OFF>(s[1], vo[1], base);
    gload<OFF>(s[2], vo[2], base);
    gload<OFF>(s[3], vo[3], base);
}
__device__ __forceinline__ void issue_bias(f32x4 bv[4], unsigned vof, const float* base) {
    gloadf<0>   (bv[0], vof, base);
    gloadf<512> (bv[1], vof, base);
    gloadf<1024>(bv[2], vof, base);
    gloadf<1536>(bv[3], vof, base);
}

// ---------------- A-fragment loads (LDS, compiler-managed lgkm) -------------
__device__ __forceinline__ void load_a0(half8 a[4], const _Float16* A0,
                                        int kc, int c, int q) {
    #pragma unroll
    for (int mt = 0; mt < 4; ++mt)
        a[mt] = *(const half8*)(A0 + (mt * 16 + c) * 72 + kc * 32 + q * 8);
}
__device__ __forceinline__ void load_aH(half8 a[4], const char* Hb,
                                        int kc, int c, int q) {
    #pragma unroll
    for (int mt = 0; mt < 4; ++mt)
        a[mt] = *(const half8*)(Hb + swz(mt * 16 + c, kc * 64 + q * 16));
}

// MFMA cluster: gates {0,2,3} if SKIPF; CIN_BV: bias as MFMA C operand.
template<bool SKIPF, bool CIN_BV>
__device__ __forceinline__ void mm(const half8 s[4], const half8 a[4],
                                   const f32x4 bv[4], f32x4 acc[4][4]) {
    __builtin_amdgcn_s_setprio(1);
    #pragma unroll
    for (int mt = 0; mt < 4; ++mt)
        #pragma unroll
        for (int g = 0; g < 4; ++g) {
            if (SKIPF && g == 1) continue;
            f32x4 cin = CIN_BV ? bv[g] : acc[mt][g];
            acc[mt][g] = __builtin_amdgcn_mfma_f32_16x16x32_f16(s[g], a[mt], cin, 0, 0, 0);
        }
    __builtin_amdgcn_s_setprio(0);
}

// KC=4 stage with counted-vmcnt ring. Ledger (outstanding after each op):
//  entry: [k0, bvX?, k1] (12 or 8)
//  kc0: WAIT4(B) -> k0(+bvX) done, k1 left | mfma | issue k2      -> k1,k2=8
//  kc1: WAIT4    -> k1 done               | mfma | issue k3      -> k2,k3=8
//  kc2: WAIT4    -> k2 done               | mfma | [bvY] [Y.k0]  -> k3,bvY,Yk0
//  kc3: WAIT4    -> k3+bvY done, Yk0 left | mfma | [Y.k1]        -> Yk0,Yk1=8
//  (PF=false: kc2 issues nothing; kc3 WAIT0 drains.)
template<bool SKIPF, bool PF, bool FIRST, bool BN>
__device__ __forceinline__ void stage4(const char* Ab, const unsigned vo[4],
                                       const _Float16* wq, const _Float16* wqn,
                                       const float* bnext, unsigned vof,
                                       half8 sA[4], half8 sB[4], f32x4 bv[4],
                                       int c, int q, f32x4 acc[4][4])
{
    // kc0
    if constexpr (FIRST) { WAIT4B(sA, bv); } else { WAIT4(sA); }
    { half8 a[4]; load_aH(a, Ab, 0, c, q); mm<SKIPF, FIRST>(sA, a, bv, acc); }
    issue4<2048>(sA, vo, wq);
    // kc1
    WAIT4(sB);
    { half8 a[4]; load_aH(a, Ab, 1, c, q); mm<SKIPF, false>(sB, a, bv, acc); }
    issue4<3072>(sB, vo, wq);
    // kc2
    WAIT4(sA);
    { half8 a[4]; load_aH(a, Ab, 2, c, q); mm<SKIPF, false>(sA, a, bv, acc); }
    if constexpr (BN) issue_bias(bv, vof, bnext);
    if constexpr (PF) issue4<0>(sA, vo, wqn);
    // kc3
    if constexpr (PF) { WAIT4(sB); } else { WAIT0(sB); }
    { half8 a[4]; load_aH(a, Ab, 3, c, q); mm<SKIPF, false>(sB, a, bv, acc); }
    if constexpr (PF) issue4<1024>(sB, vo, wqn);
}

__global__ __launch_bounds__(512) void lstm_main(
    const float* __restrict__ x, const _Float16* __restrict__ Wp_in,
    const float* __restrict__ bias0f_in, const float* __restrict__ bias1f_in,
    const float* __restrict__ mu_g2_in, const float* __restrict__ fc_w_in,
    const float* __restrict__ fc_b_in, float* __restrict__ out)
{
    // LDS 49152 B: H1s [0,16K) | H2s [16K,32K) (A0 aliased) | H11s [32K,48K)
    __shared__ __align__(16) char smem[49152];
    char* H1s  = smem;
    char* H2s  = smem + 16384;
    char* H11s = smem + 32768;
    _Float16* A0 = (_Float16*)(smem + 16384);    // alias of H2s region

    const int t = threadIdx.x;
    const int w = t >> 6, lane = t & 63, c = lane & 15, q = lane >> 4;
    const int wg = blockIdx.x;                   // 1024 wgs x 64 rows
    const int b = wg >> 4;                       // 16 wgs (1024 rows) per batch
    const int bq_idx = w * 4 + q;                // float4 index of (w,q) slice

    // SGPR stage bases
    const _Float16* wS1  = Wp_in + WP_WIH0;
    const _Float16* wS2  = Wp_in + WP_WHH0;
    const _Float16* wS3  = Wp_in + WP_WIH1;     // also S4a
    const _Float16* wS4b = Wp_in + WP_WHH1;
    const float* mu_g2b  = mu_g2_in + b * 512;

    // VGPR addressing: voA (S1, KC=2 pack stride) / voB (KC=4 stages) / vof
    unsigned voA[4], voB[4];
    #pragma unroll
    for (int g = 0; g < 4; ++g) {
        voA[g] = (unsigned)(((g * 8 + w) * 1024 + lane * 8) * 2);   // bytes
        voB[g] = (unsigned)(((g * 8 + w) * 2048 + lane * 8) * 2);   // bytes
    }
    unsigned vof = (unsigned)(bq_idx * 16);

    // ---- pipeline prologue: S1.k0 ; bias0 ; S1.k1 (order = vmcnt ledger) --
    half8 sA[4], sB[4];
    f32x4 bv[4];
    issue4<0>(sA, voA, wS1);
    issue_bias(bv, vof, bias0f_in);
    issue4<1024>(sB, voA, wS1);

    // ---- preamble: stage x tile into A0 (coalesced); init out rows --------
    {
        const float* xp = x + (size_t)wg * 4096 + t * 8;
        float4 u0 = ((const float4*)xp)[0];
        float4 u1 = ((const float4*)xp)[1];
        half8 hv;
        hv[0] = (_Float16)u0.x; hv[1] = (_Float16)u0.y;
        hv[2] = (_Float16)u0.z; hv[3] = (_Float16)u0.w;
        hv[4] = (_Float16)u1.x; hv[5] = (_Float16)u1.y;
        hv[6] = (_Float16)u1.z; hv[7] = (_Float16)u1.w;
        *(half8*)(A0 + (t >> 3) * 72 + (t & 7) * 8) = hv;
        if (t < 64) out[(size_t)wg * 64 + t] = fc_b_in[0];
    }
    lds_barrier();   // A0 visible (lgkm only; weight/bias loads stay in flight)

    f32x4 acc[4][4];
    float cc[4][4];

    // ---- S1 (KC=2, A from A0, SKIPF, bias0 as C) --------------------------
    // ledger: entry [k0,bv0,k1]=12
    WAIT4B(sA, bv);                              // k0+bv0 done, k1 left
    { half8 a[4]; load_a0(a, A0, 0, c, q); mm<true, true>(sA, a, bv, acc); }
    issue_bias(bv, vof, mu_g2b);                 // k1,bvmu = 8
    issue4<0>(sA, voB, wS2);                     // k1,bvmu,S2k0 = 12
    WAIT4(sB);                                   // k1+bvmu done, S2k0 left
    { half8 a[4]; load_a0(a, A0, 1, c, q); mm<true, false>(sB, a, bv, acc); }
    issue4<1024>(sB, voB, wS2);                  // S2k0,S2k1 = 8 through epi1
    // epi1: c1 = sig*tanh fused; h1 -> H1s
    #pragma unroll
    for (int mt = 0; mt < 4; ++mt) {
        half4_t hv;
        #pragma unroll
        for (int r = 0; r < 4; ++r) {
            float c1 = sigtanh(acc[mt][0][r], acc[mt][2][r]);
            cc[mt][r] = c1;
            hv[r] = (_Float16)sigtanh(acc[mt][3][r], c1 * L2E2);
        }
        *(half4_t*)(H1s + swz(mt * 16 + c, w * 32 + q * 8)) = hv;
    }
    lds_barrier();   // [S1-barrier] H1s ready; A0 dead; S2 loads in flight

    // ---- S2 (A from H1s; mu_g2 as C; all gates; prefetch S3 + bias1) ------
    stage4<false, true, true, true>(H1s, voB, wS2, wS3, bias1f_in, vof,
                                    sA, sB, bv, c, q, acc);
    // epi2: c2 = sig(f)*c1 + fused; h2 -> H2s (no barrier: S3 reads H1s)
    #pragma unroll
    for (int mt = 0; mt < 4; ++mt) {
        half4_t hv;
        #pragma unroll
        for (int r = 0; r < 4; ++r) {
            float c2 = sig2(acc[mt][1][r]) * cc[mt][r]
                     + sigtanh(acc[mt][0][r], acc[mt][2][r]);
            hv[r] = (_Float16)sigtanh(acc[mt][3][r], c2 * L2E2);
        }
        *(half4_t*)(H2s + swz(mt * 16 + c, w * 32 + q * 8)) = hv;
    }

    // ---- S3 (A from H1s; bias1 as C; SKIPF; prefetch S4a + bias1 again) ---
    stage4<true, true, true, true>(H1s, voB, wS3, wS3, bias1f_in, vof,
                                   sA, sB, bv, c, q, acc);
    // epi3: h11 -> H11s, cc := layer-1 c1
    #pragma unroll
    for (int mt = 0; mt < 4; ++mt) {
        half4_t hv;
        #pragma unroll
        for (int r = 0; r < 4; ++r) {
            float c1 = sigtanh(acc[mt][0][r], acc[mt][2][r]);
            cc[mt][r] = c1;
            hv[r] = (_Float16)sigtanh(acc[mt][3][r], c1 * L2E2);
        }
        *(half4_t*)(H11s + swz(mt * 16 + c, w * 32 + q * 8)) = hv;
    }
    lds_barrier();   // [S3-barrier] H2s + H11s ready; S4a loads in flight

    // ---- S4a (A from H2s; bias1 as C; prefetch S4b, no next-bias) ---------
    stage4<false, true, true, false>(H2s, voB, wS3, wS4b, nullptr, vof,
                                     sA, sB, bv, c, q, acc);
    // ---- S4b (A from H11s; accumulate; no prefetch, final drain) ----------
    stage4<false, false, false, false>(H11s, voB, wS4b, nullptr, nullptr, vof,
                                       sA, sB, bv, c, q, acc);

    // epilogue: h2_1 -> relu -> dot fc_w; partials straight to L2 atomics
    {
        const float* fc_w = fc_w_in; asm volatile("" : "+s"(fc_w));
        f32x4 fwv = ((const f32x4*)fc_w)[bq_idx];
        #pragma unroll
        for (int mt = 0; mt < 4; ++mt) {
            float v = 0.0f;
            #pragma unroll
            for (int r = 0; r < 4; ++r) {
                float c2 = sig2(acc[mt][1][r]) * cc[mt][r]
                         + sigtanh(acc[mt][0][r], acc[mt][2][r]);
                float h  = sigtanh(acc[mt][3][r], c2 * L2E2);
                v = fmaf(fmaxf(h, 0.0f), fwv[r], v);
            }
            v += __shfl_xor(v, 16);
            v += __shfl_xor(v, 32);
            if (lane < 16)
                atomicAdd(out + (size_t)wg * 64 + mt * 16 + lane, v);
        }
    }
}

extern "C" void kernel_launch(void* const* d_in, const int* in_sizes, int n_in,
                              void* d_out, int out_size, void* d_ws, size_t ws_size,
                              hipStream_t stream)
{
    const float* x    = (const float*)d_in[0];
    const float* mu   = (const float*)d_in[1];
    const float* Wih0 = (const float*)d_in[2];
    const float* Whh0 = (const float*)d_in[3];
    const float* bih0 = (const float*)d_in[4];
    const float* bhh0 = (const float*)d_in[5];
    const float* Wih1 = (const float*)d_in[6];
    const float* Whh1 = (const float*)d_in[7];
    const float* bih1 = (const float*)d_in[8];
    const float* bhh1 = (const float*)d_in[9];
    const float* fcw  = (const float*)d_in[10];
    const float* fcb  = (const float*)d_in[11];
    float* out = (float*)d_out;

    _Float16* Wp  = (_Float16*)d_ws;
    float* bias0f = (float*)((char*)d_ws + WS_BIAS0);
    float* bias1f = (float*)((char*)d_ws + WS_BIAS1);
    float* mu_g2  = (float*)((char*)d_ws + WS_MUG2);

    hipLaunchKernelGGL(prep_kernel, dim3(241), dim3(256), 0, stream,
                       Wih0, Whh0, Wih1, Whh1, bih0, bhh0, bih1, bhh1, mu,
                       Wp, bias0f, bias1f, mu_g2);
    hipLaunchKernelGGL(lstm_main, dim3(1024), dim3(512), 0, stream,
                       x, Wp, bias0f, bias1f, mu_g2, fcw, fcb, out);
}

// Round 14
// 134.974 us; speedup vs baseline: 1.0071x; 1.0071x over previous
//
#include <hip/hip_runtime.h>

// Forecaster: B=64, S=1024, F=64, H=128. N = B*S = 65536 independent instances.
// R22b (compile fix: macros removed, operands inlined — R13's bench failed
// on use-before-definition of a_cur/acc_sel; hypothesis never tested).
// A-fragment cross-kc double-buffer. R21 post-mortem: asm counted-vmcnt
// REGRESSED (60.5->64.6; third proof that hand-pinning order loses to the
// compiler here). Reverted to R19 state. Elimination table: occupancy(R15),
// HIP-depth(R16), residency(R18), volume(R19), phase(R20) all null;
// asm-vmcnt(R21) negative. Last untested latency source: per-kc LDS a-frag
// reads (~120cyc ds_read_b128 latency, m117/m134) issued immediately before
// their consuming MFMAs — 18 kc-steps of exposed LDS latency. Weights got
// the 1-iter-lead treatment in R14 (+12%); A-frags never did.
// Single change vs R19 (math identical):
//  - gemm_pf carries aC/aN: kc+1's 4 ds_read_b128 issue BEFORE kc's MFMA
//    cluster (latency hides under ~80cyc of MFMA + bq issues). Fully
//    unrolled -> SSA renaming, no v_mov copies. Stage-head load exposed
//    once per stage (6x ~100cyc) instead of per kc (18x).
//  - s_sleep removed (R20 null).
// Kept: R19 sigtanh fusion + f-gate MFMA skip; R15 geometry (grid 1024,
// 64-row wgs); R14 bq prefetch + lgkm-only barriers + bias-as-MFMA-C;
// A0 aliases H2s (LDS 49152); swizzled H tiles; setprio; plain
// __launch_bounds__(512).
// ABORT criteria: VGPR>128 (bucket cliff) or WRITE_SIZE>3MB (spill).
// NEVER: min-waves clamp (R12/R17); asm-pinned schedules (R13/R21).

typedef _Float16 half8 __attribute__((ext_vector_type(8)));
typedef _Float16 half4_t __attribute__((ext_vector_type(4)));
typedef float f32x4 __attribute__((ext_vector_type(4)));

#define L2E  1.4426950408889634f
#define L2E2 2.8853900817779268f

#define WP_WIH0 0
#define WP_WHH0 32768
#define WP_WIH1 98304
#define WP_WHH1 163840
#define WS_BIAS0 458752            // bytes
#define WS_BIAS1 (458752 + 2048)
#define WS_MUG2  (458752 + 4096)

// ---------------- merged prep kernel (unchanged) ----------------------------
__global__ void prep_kernel(const float* __restrict__ Wih0,
                            const float* __restrict__ Whh0,
                            const float* __restrict__ Wih1,
                            const float* __restrict__ Whh1,
                            const float* __restrict__ bih0,
                            const float* __restrict__ bhh0,
                            const float* __restrict__ bih1,
                            const float* __restrict__ bhh1,
                            const float* __restrict__ mu,
                            _Float16* __restrict__ Wp,
                            float* __restrict__ bias0f,
                            float* __restrict__ bias1f,
                            float* __restrict__ mu_g2)
{
    int blk = blockIdx.x;
    if (blk >= 113) {                       // ---- mu_g2 part
        int o = (blk - 113) * 256 + threadIdx.x;   // 0..32767
        int b = o >> 9;
        int n = o & 511;
        float s = bih0[n] + bhh0[n];
        const float* m = mu + b * 64;
        const float* wrow = Wih0 + n * 64;
        #pragma unroll 8
        for (int k = 0; k < 64; ++k) s += m[k] * wrow[k];
        float scale = ((n >> 7) == 2) ? L2E2 : L2E;
        mu_g2[o] = s * scale;
        return;
    }
    if (blk == 112) {                       // ---- bias part
        int i = threadIdx.x;
        float sc_hi = (i < 128) ? L2E2 : L2E;
        bias0f[i]       = (bih0[i]       + bhh0[i])       * L2E;
        bias0f[i + 256] = (bih0[i + 256] + bhh0[i + 256]) * sc_hi;
        bias1f[i]       = (bih1[i]       + bhh1[i])       * L2E;
        bias1f[i + 256] = (bih1[i + 256] + bhh1[i + 256]) * sc_hi;
        return;
    }
    // ---- weight pack: [nt][kc][lane][8], c=lane&15 -> n=nt*16+c,
    //      q=lane>>4 -> k = kc*32 + q*8 .. +8  (scaled by gate)
    int gidx = blk * 256 + threadIdx.x;     // 0..28671 groups of 8 halfs
    const float* src; int KC, Kw, local;
    if (gidx < 4096)       { src = Wih0; KC = 2; Kw = 64;  local = gidx; }
    else if (gidx < 12288) { src = Whh0; KC = 4; Kw = 128; local = gidx - 4096; }
    else if (gidx < 20480) { src = Wih1; KC = 4; Kw = 128; local = gidx - 12288; }
    else                   { src = Whh1; KC = 4; Kw = 128; local = gidx - 20480; }
    int lane = local & 63;
    int tmp  = local >> 6;
    int kc   = tmp % KC;
    int nt   = tmp / KC;
    int n  = nt * 16 + (lane & 15);
    int k0 = kc * 32 + (lane >> 4) * 8;
    float scale = ((n >> 7) == 2) ? L2E2 : L2E;
    const float* s = src + n * Kw + k0;
    half8 hv;
    #pragma unroll
    for (int j = 0; j < 8; ++j) hv[j] = (_Float16)(s[j] * scale);
    *(half8*)(Wp + (size_t)gidx * 8) = hv;
}

// ---------------- bare-metal gate math -------------------------------------
__device__ __forceinline__ float sig2(float a) {
    return __builtin_amdgcn_rcpf(1.0f + __builtin_amdgcn_exp2f(-a));
}
// Fused sig(x̂)·tanh(ŷ): 3 trans instead of 4 (R19).
__device__ __forceinline__ float sigtanh(float xs, float yt) {
    float d = __builtin_amdgcn_exp2f(-xs);
    float e = __builtin_amdgcn_exp2f(yt);
    return (e - 1.0f) * __builtin_amdgcn_rcpf((1.0f + d) * (1.0f + e));
}

// Swizzled byte offset into a [64 rows][256B] H tile (involution; same on
// write and read).
__device__ __forceinline__ int swz(int row, int col) {
    return (row << 8) + (col ^ ((row & 7) << 4));
}

// lgkm-only barrier: orders LDS traffic across the wg WITHOUT draining vmcnt,
// so prefetched global weight loads stay in flight across it (T3/T4).
__device__ __forceinline__ void lds_barrier() {
    asm volatile("s_waitcnt lgkmcnt(0)" ::: "memory");
    __builtin_amdgcn_s_barrier();
    asm volatile("" ::: "memory");
}

// SKIPF: skip gate g=1 (f-gate) — step-1 stages never consume it.
template<bool SKIPF>
__device__ __forceinline__ void load_bq(half8 bq[4], const _Float16* __restrict__ Wq,
                                        int KC, int kc, int w, int lane)
{
    #pragma unroll
    for (int g = 0; g < 4; ++g) {
        if (SKIPF && g == 1) continue;
        bq[g] = *(const half8*)(Wq + (((g * 8 + w) * KC + kc) * 64 + lane) * 8);
    }
}

template<int SRC>   // 0 = A0 (stride 72 halfs), 1 = swizzled H tile
__device__ __forceinline__ void load_a(half8 a[4], const char* base, int kc, int c, int q)
{
    #pragma unroll
    for (int mt = 0; mt < 4; ++mt) {
        if (SRC == 0)
            a[mt] = *(const half8*)((const _Float16*)base + (mt * 16 + c) * 72 + kc * 32 + q * 8);
        else
            a[mt] = *(const half8*)(base + swz(mt * 16 + c, kc * 64 + q * 16));
    }
}

// One gemm stage, 1-deep double-buffer on BOTH operands:
//  - bq (global weights): kc+1 issued during kc's MFMAs (R14, +12%).
//  - a  (LDS fragments):  kc+1's ds_read_b128 issued BEFORE kc's MFMAs, so
//    the ~120cyc LDS latency hides under the MFMA cluster (R22).
// SKIPF: this stage uses gates {0,2,3}. NSKIPF: next stage's gate-set.
// FIRST: bv[g] is the MFMA C operand at kc=0 (bias init without v_movs).
template<int KC, int SRC, bool PF, bool FIRST, bool SKIPF, bool NSKIPF>
__device__ __forceinline__ void gemm_pf(const _Float16* __restrict__ Wq,
                                        const char* Abase,
                                        const _Float16* __restrict__ Wnext, int KCnext,
                                        half8 bqc[4], const f32x4 bv[4],
                                        int w, int lane, f32x4 acc[4][4])
{
    const int c = lane & 15, q = lane >> 4;
    half8 aC[4], aN[4];
    load_a<SRC>(aC, Abase, 0, c, q);
    #pragma unroll
    for (int kc = 0; kc < KC; ++kc) {
        if (kc + 1 < KC) load_a<SRC>(aN, Abase, kc + 1, c, q);
        half8 bqn[4];
        if (kc + 1 < KC)  load_bq<SKIPF>(bqn, Wq, KC, kc + 1, w, lane);
        else if (PF)      load_bq<NSKIPF>(bqn, Wnext, KCnext, 0, w, lane);
        __builtin_amdgcn_s_setprio(1);
        #pragma unroll
        for (int mt = 0; mt < 4; ++mt)
            #pragma unroll
            for (int g = 0; g < 4; ++g) {
                if (SKIPF && g == 1) continue;
                f32x4 cin = (FIRST && kc == 0) ? bv[g] : acc[mt][g];
                acc[mt][g] = __builtin_amdgcn_mfma_f32_16x16x32_f16(bqc[g], aC[mt], cin, 0, 0, 0);
            }
        __builtin_amdgcn_s_setprio(0);
        if (kc + 1 < KC) {
            #pragma unroll
            for (int mt = 0; mt < 4; ++mt) aC[mt] = aN[mt];
            #pragma unroll
            for (int g = 0; g < 4; ++g)
                if (!(SKIPF && g == 1)) bqc[g] = bqn[g];
        } else if (PF) {
            #pragma unroll
            for (int g = 0; g < 4; ++g)
                if (!(NSKIPF && g == 1)) bqc[g] = bqn[g];
        }
    }
}

__global__ __launch_bounds__(512) void lstm_main(
    const float* __restrict__ x, const _Float16* __restrict__ Wp_in,
    const float* __restrict__ bias0f_in, const float* __restrict__ bias1f_in,
    const float* __restrict__ mu_g2_in, const float* __restrict__ fc_w_in,
    const float* __restrict__ fc_b_in, float* __restrict__ out)
{
    // LDS 49152 B:
    //  [0, 16384)       H1s   (swizzled [64][256B])
    //  [16384, 32768)   H2s   -- ALSO hosts A0 (64 x 72 halfs = 9216 B):
    //                      A0 dead at S1-barrier (lgkmcnt(0) drains its
    //                      ds_reads); H2s first written in epi2 after it.
    //  [32768, 49152)   H11s
    __shared__ __align__(16) char smem[49152];
    char* H1s  = smem;
    char* H2s  = smem + 16384;
    char* H11s = smem + 32768;
    _Float16* A0 = (_Float16*)(smem + 16384);    // alias of H2s region

    const int t = threadIdx.x;
    const int w = t >> 6, lane = t & 63, c = lane & 15, q = lane >> 4;
    const int wg = blockIdx.x;                   // 1024 wgs x 64 rows
    const int b = wg >> 4;                       // 16 wgs (1024 rows) per batch
    const int bq_idx = w * 4 + q;                // float4 index of (w,q) slice

    // ---- prefetch S1 kc=0 weights {i,g,o} with maximum lead ---------------
    half8 bqc[4];
    load_bq<true>(bqc, Wp_in + WP_WIH0, 2, 0, w, lane);

    // ---- preamble: stage x tile into A0 (coalesced); init out rows --------
    {
        const float* xp = x + (size_t)wg * 4096 + t * 8;
        float4 u0 = ((const float4*)xp)[0];
        float4 u1 = ((const float4*)xp)[1];
        half8 hv;
        hv[0] = (_Float16)u0.x; hv[1] = (_Float16)u0.y;
        hv[2] = (_Float16)u0.z; hv[3] = (_Float16)u0.w;
        hv[4] = (_Float16)u1.x; hv[5] = (_Float16)u1.y;
        hv[6] = (_Float16)u1.z; hv[7] = (_Float16)u1.w;
        *(half8*)(A0 + (t >> 3) * 72 + (t & 7) * 8) = hv;
        if (t < 64) out[(size_t)wg * 64 + t] = fc_b_in[0];
    }
    lds_barrier();   // A0 visible (lgkm); weight prefetch still in flight

    f32x4 acc[4][4];
    float cc[4][4];

    // ---- S1: layer0 step1 (A from A0; bias0 as C; gates {i,g,o}) ----------
    {
        f32x4 bv[4];
        {
            const float* bias0f = bias0f_in; asm volatile("" : "+s"(bias0f));
            #pragma unroll
            for (int g = 0; g < 4; ++g)
                if (g != 1) bv[g] = ((const f32x4*)bias0f)[g * 32 + bq_idx];
        }
        gemm_pf<2, 0, true, true, true, false>(
            Wp_in + WP_WIH0, (const char*)A0,
            Wp_in + WP_WHH0, 4, bqc, bv, w, lane, acc);
    }
    // epi1: c1 = sig(i)tanh(g) [fused]; h1 = sig(o)tanh(c1) [fused]
    #pragma unroll
    for (int mt = 0; mt < 4; ++mt) {
        half4_t hv;
        #pragma unroll
        for (int r = 0; r < 4; ++r) {
            float c1 = sigtanh(acc[mt][0][r], acc[mt][2][r]);
            cc[mt][r] = c1;
            hv[r] = (_Float16)sigtanh(acc[mt][3][r], c1 * L2E2);
        }
        *(half4_t*)(H1s + swz(mt * 16 + c, w * 32 + q * 8)) = hv;
    }
    lds_barrier();   // [S1-barrier] H1s ready; A0 dead; Whh0 kc=0 in flight

    // ---- S2: layer0 step2 (A from H1s; mu_g2 as C; all gates) -------------
    // Tail prefetches Wih1 kc=0 for S3 (gates {i,g,o}).
    {
        f32x4 bv[4];
        {
            const float* mu_g2b = mu_g2_in + b * 512; asm volatile("" : "+s"(mu_g2b));
            #pragma unroll
            for (int g = 0; g < 4; ++g)
                bv[g] = ((const f32x4*)mu_g2b)[g * 32 + bq_idx];
        }
        gemm_pf<4, 1, true, true, false, true>(
            Wp_in + WP_WHH0, H1s,
            Wp_in + WP_WIH1, 4, bqc, bv, w, lane, acc);
    }
    // epi2: c2 = sig(f)*c1 + sig(i)tanh(g) [fused]; h2 = sig(o)tanh(c2) [fused]
    #pragma unroll
    for (int mt = 0; mt < 4; ++mt) {
        half4_t hv;
        #pragma unroll
        for (int r = 0; r < 4; ++r) {
            float c2 = sig2(acc[mt][1][r]) * cc[mt][r]
                     + sigtanh(acc[mt][0][r], acc[mt][2][r]);
            hv[r] = (_Float16)sigtanh(acc[mt][3][r], c2 * L2E2);
        }
        *(half4_t*)(H2s + swz(mt * 16 + c, w * 32 + q * 8)) = hv;
    }

    // ---- S3: layer1 step1 (A from H1s; bias1 as C; gates {i,g,o}) ---------
    // Tail prefetches Wih1 kc=0 for S4a (all gates; L2-hot).
    {
        f32x4 bv[4];
        {
            const float* bias1f = bias1f_in; asm volatile("" : "+s"(bias1f));
            #pragma unroll
            for (int g = 0; g < 4; ++g)
                if (g != 1) bv[g] = ((const f32x4*)bias1f)[g * 32 + bq_idx];
        }
        gemm_pf<4, 1, true, true, true, false>(
            Wp_in + WP_WIH1, H1s,
            Wp_in + WP_WIH1, 4, bqc, bv, w, lane, acc);
    }
    // epi3: h11 -> H11s, cc := layer-1 c1 (both fused)
    #pragma unroll
    for (int mt = 0; mt < 4; ++mt) {
        half4_t hv;
        #pragma unroll
        for (int r = 0; r < 4; ++r) {
            float c1 = sigtanh(acc[mt][0][r], acc[mt][2][r]);
            cc[mt][r] = c1;
            hv[r] = (_Float16)sigtanh(acc[mt][3][r], c1 * L2E2);
        }
        *(half4_t*)(H11s + swz(mt * 16 + c, w * 32 + q * 8)) = hv;
    }
    lds_barrier();   // [S3-barrier] H2s + H11s ready; Wih1 kc=0 in flight

    // ---- S4: layer1 step2 (Wih1@H2s + Whh1@H11s; bias1 as C; all gates) ---
    {
        f32x4 bv[4];
        {
            const float* bias1f = bias1f_in; asm volatile("" : "+s"(bias1f));
            #pragma unroll
            for (int g = 0; g < 4; ++g)
                bv[g] = ((const f32x4*)bias1f)[g * 32 + bq_idx];
        }
        gemm_pf<4, 1, true, true, false, false>(
            Wp_in + WP_WIH1, H2s,
            Wp_in + WP_WHH1, 4, bqc, bv, w, lane, acc);
    }
    gemm_pf<4, 1, false, false, false, false>(
        Wp_in + WP_WHH1, H11s,
        nullptr, 0, bqc, nullptr, w, lane, acc);

    // epilogue: h2_1 -> relu -> dot fc_w; partials straight to L2 atomics
    // (out pre-inited with fc_b in preamble; only this wg touches these 64
    //  rows; the store retires during the intervening vmcnt traffic).
    {
        const float* fc_w = fc_w_in; asm volatile("" : "+s"(fc_w));
        f32x4 fwv = ((const f32x4*)fc_w)[bq_idx];
        #pragma unroll
        for (int mt = 0; mt < 4; ++mt) {
            float v = 0.0f;
            #pragma unroll
            for (int r = 0; r < 4; ++r) {
                float c2 = sig2(acc[mt][1][r]) * cc[mt][r]
                         + sigtanh(acc[mt][0][r], acc[mt][2][r]);
                float h  = sigtanh(acc[mt][3][r], c2 * L2E2);
                v = fmaf(fmaxf(h, 0.0f), fwv[r], v);
            }
            v += __shfl_xor(v, 16);
            v += __shfl_xor(v, 32);
            if (lane < 16)
                atomicAdd(out + (size_t)wg * 64 + mt * 16 + lane, v);
        }
    }
}

extern "C" void kernel_launch(void* const* d_in, const int* in_sizes, int n_in,
                              void* d_out, int out_size, void* d_ws, size_t ws_size,
                              hipStream_t stream)
{
    const float* x    = (const float*)d_in[0];
    const float* mu   = (const float*)d_in[1];
    const float* Wih0 = (const float*)d_in[2];
    const float* Whh0 = (const float*)d_in[3];
    const float* bih0 = (const float*)d_in[4];
    const float* bhh0 = (const float*)d_in[5];
    const float* Wih1 = (const float*)d_in[6];
    const float* Whh1 = (const float*)d_in[7];
    const float* bih1 = (const float*)d_in[8];
    const float* bhh1 = (const float*)d_in[9];
    const float* fcw  = (const float*)d_in[10];
    const float* fcb  = (const float*)d_in[11];
    float* out = (float*)d_out;

    _Float16* Wp  = (_Float16*)d_ws;
    float* bias0f = (float*)((char*)d_ws + WS_BIAS0);
    float* bias1f = (float*)((char*)d_ws + WS_BIAS1);
    float* mu_g2  = (float*)((char*)d_ws + WS_MUG2);

    hipLaunchKernelGGL(prep_kernel, dim3(241), dim3(256), 0, stream,
                       Wih0, Whh0, Wih1, Whh1, bih0, bhh0, bih1, bhh1, mu,
                       Wp, bias0f, bias1f, mu_g2);
    hipLaunchKernelGGL(lstm_main, dim3(1024), dim3(512), 0, stream,
                       x, Wp, bias0f, bias1f, mu_g2, fcw, fcb, out);
}

// Round 15
// 132.115 us; speedup vs baseline: 1.0289x; 1.0216x over previous
//
#include <hip/hip_runtime.h>

// Forecaster: B=64, S=1024, F=64, H=128. N = B*S = 65536 independent instances.
// R23: REVERT to R19 — the session's best-measured state (lstm_main
// 60.4-61.9us, harness 132.7us). R22b's A-frag double-buffer was the last
// untested latency mechanism and regressed (62.6-63.9, VGPR 92).
// Final elimination table (9 experiments):
//   R14 weight-prefetch+lgkm-barriers+bias-as-C: -12us (the win)
//   R15 occupancy/LDS: null | R16 HIP 2-deep: null | R17 clamp: disaster
//   R18 residency: -2us | R19 trans -22%: null-in-time | R20 stagger: null
//   R21 asm vmcnt: -4us | R22 a-frag dbuf: -2us
// Issue-cycle floor ~24-30us vs 61us actual; the gap resisted six
// independent mechanisms. Remaining idea (merged S2+S3, 32-row wgs) prices
// at ~148 VGPR pre-trim — over the 128 bucket. Plateau declared.
// Kernel = R19: sigtanh fusion (3 trans/pair) + f-gate MFMA skip + R14
// pipeline + lgkm-only barriers + bias-as-MFMA-C + A0-aliases-H2s (LDS
// 49152) + swizzled H tiles + setprio; grid 1024 x 512thr; plain
// __launch_bounds__(512).
// NEVER: min-waves clamp (R12/R17); asm-pinned schedules (R13/R21).

typedef _Float16 half8 __attribute__((ext_vector_type(8)));
typedef _Float16 half4_t __attribute__((ext_vector_type(4)));
typedef float f32x4 __attribute__((ext_vector_type(4)));

#define L2E  1.4426950408889634f
#define L2E2 2.8853900817779268f

#define WP_WIH0 0
#define WP_WHH0 32768
#define WP_WIH1 98304
#define WP_WHH1 163840
#define WS_BIAS0 458752            // bytes
#define WS_BIAS1 (458752 + 2048)
#define WS_MUG2  (458752 + 4096)

// ---------------- merged prep kernel (unchanged) ----------------------------
__global__ void prep_kernel(const float* __restrict__ Wih0,
                            const float* __restrict__ Whh0,
                            const float* __restrict__ Wih1,
                            const float* __restrict__ Whh1,
                            const float* __restrict__ bih0,
                            const float* __restrict__ bhh0,
                            const float* __restrict__ bih1,
                            const float* __restrict__ bhh1,
                            const float* __restrict__ mu,
                            _Float16* __restrict__ Wp,
                            float* __restrict__ bias0f,
                            float* __restrict__ bias1f,
                            float* __restrict__ mu_g2)
{
    int blk = blockIdx.x;
    if (blk >= 113) {                       // ---- mu_g2 part
        int o = (blk - 113) * 256 + threadIdx.x;   // 0..32767
        int b = o >> 9;
        int n = o & 511;
        float s = bih0[n] + bhh0[n];
        const float* m = mu + b * 64;
        const float* wrow = Wih0 + n * 64;
        #pragma unroll 8
        for (int k = 0; k < 64; ++k) s += m[k] * wrow[k];
        float scale = ((n >> 7) == 2) ? L2E2 : L2E;
        mu_g2[o] = s * scale;
        return;
    }
    if (blk == 112) {                       // ---- bias part
        int i = threadIdx.x;
        float sc_hi = (i < 128) ? L2E2 : L2E;
        bias0f[i]       = (bih0[i]       + bhh0[i])       * L2E;
        bias0f[i + 256] = (bih0[i + 256] + bhh0[i + 256]) * sc_hi;
        bias1f[i]       = (bih1[i]       + bhh1[i])       * L2E;
        bias1f[i + 256] = (bih1[i + 256] + bhh1[i + 256]) * sc_hi;
        return;
    }
    // ---- weight pack: [nt][kc][lane][8], c=lane&15 -> n=nt*16+c,
    //      q=lane>>4 -> k = kc*32 + q*8 .. +8  (scaled by gate)
    int gidx = blk * 256 + threadIdx.x;     // 0..28671 groups of 8 halfs
    const float* src; int KC, Kw, local;
    if (gidx < 4096)       { src = Wih0; KC = 2; Kw = 64;  local = gidx; }
    else if (gidx < 12288) { src = Whh0; KC = 4; Kw = 128; local = gidx - 4096; }
    else if (gidx < 20480) { src = Wih1; KC = 4; Kw = 128; local = gidx - 12288; }
    else                   { src = Whh1; KC = 4; Kw = 128; local = gidx - 20480; }
    int lane = local & 63;
    int tmp  = local >> 6;
    int kc   = tmp % KC;
    int nt   = tmp / KC;
    int n  = nt * 16 + (lane & 15);
    int k0 = kc * 32 + (lane >> 4) * 8;
    float scale = ((n >> 7) == 2) ? L2E2 : L2E;
    const float* s = src + n * Kw + k0;
    half8 hv;
    #pragma unroll
    for (int j = 0; j < 8; ++j) hv[j] = (_Float16)(s[j] * scale);
    *(half8*)(Wp + (size_t)gidx * 8) = hv;
}

// ---------------- bare-metal gate math -------------------------------------
__device__ __forceinline__ float sig2(float a) {
    return __builtin_amdgcn_rcpf(1.0f + __builtin_amdgcn_exp2f(-a));
}
// Fused sig(x̂)·tanh(ŷ): x̂ = x·L2E (sigmoid arg), ŷ = y·L2E2 (tanh arg).
//   sig·tanh = (e-1) / ((1+d)(1+e)),  d = exp2(-x̂), e = exp2(ŷ)
// 3 trans (2 exp2 + 1 rcp) vs 4 in the separate forms.
__device__ __forceinline__ float sigtanh(float xs, float yt) {
    float d = __builtin_amdgcn_exp2f(-xs);
    float e = __builtin_amdgcn_exp2f(yt);
    return (e - 1.0f) * __builtin_amdgcn_rcpf((1.0f + d) * (1.0f + e));
}

// Swizzled byte offset into a [64 rows][256B] H tile (involution; same on
// write and read).
__device__ __forceinline__ int swz(int row, int col) {
    return (row << 8) + (col ^ ((row & 7) << 4));
}

// lgkm-only barrier: orders LDS traffic across the wg WITHOUT draining vmcnt,
// so prefetched global weight loads stay in flight across it (T3/T4).
__device__ __forceinline__ void lds_barrier() {
    asm volatile("s_waitcnt lgkmcnt(0)" ::: "memory");
    __builtin_amdgcn_s_barrier();
    asm volatile("" ::: "memory");
}

// SKIPF: skip gate g=1 (f-gate) — step-1 stages never consume it.
template<bool SKIPF>
__device__ __forceinline__ void load_bq(half8 bq[4], const _Float16* __restrict__ Wq,
                                        int KC, int kc, int w, int lane)
{
    #pragma unroll
    for (int g = 0; g < 4; ++g) {
        if (SKIPF && g == 1) continue;
        bq[g] = *(const half8*)(Wq + (((g * 8 + w) * KC + kc) * 64 + lane) * 8);
    }
}

template<int SRC>   // 0 = A0 (stride 72 halfs), 1 = swizzled H tile
__device__ __forceinline__ void load_a(half8 a[4], const char* base, int kc, int c, int q)
{
    #pragma unroll
    for (int mt = 0; mt < 4; ++mt) {
        if (SRC == 0)
            a[mt] = *(const half8*)((const _Float16*)base + (mt * 16 + c) * 72 + kc * 32 + q * 8);
        else
            a[mt] = *(const half8*)(base + swz(mt * 16 + c, kc * 64 + q * 16));
    }
}

// One gemm stage, 1-deep bq double-buffer. SKIPF: this stage uses gates
// {0,2,3} only. NSKIPF: the NEXT stage's gate-set (for the tail prefetch).
// On entry bqc holds this stage's kc=0 quads; on exit (PF) the next stage's.
// FIRST: bv[g] is the MFMA C operand at kc=0 (bias init without v_movs).
template<int KC, int SRC, bool PF, bool FIRST, bool SKIPF, bool NSKIPF>
__device__ __forceinline__ void gemm_pf(const _Float16* __restrict__ Wq,
                                        const char* Abase,
                                        const _Float16* __restrict__ Wnext, int KCnext,
                                        half8 bqc[4], const f32x4 bv[4],
                                        int w, int lane, f32x4 acc[4][4])
{
    const int c = lane & 15, q = lane >> 4;
    #pragma unroll
    for (int kc = 0; kc < KC; ++kc) {
        half8 bqn[4];
        if (kc + 1 < KC)  load_bq<SKIPF>(bqn, Wq, KC, kc + 1, w, lane);
        else if (PF)      load_bq<NSKIPF>(bqn, Wnext, KCnext, 0, w, lane);
        half8 a[4];
        load_a<SRC>(a, Abase, kc, c, q);
        __builtin_amdgcn_s_setprio(1);
        #pragma unroll
        for (int mt = 0; mt < 4; ++mt)
            #pragma unroll
            for (int g = 0; g < 4; ++g) {
                if (SKIPF && g == 1) continue;
                f32x4 cin = (FIRST && kc == 0) ? bv[g] : acc[mt][g];
                acc[mt][g] = __builtin_amdgcn_mfma_f32_16x16x32_f16(bqc[g], a[mt], cin, 0, 0, 0);
            }
        __builtin_amdgcn_s_setprio(0);
        if (kc + 1 < KC) {
            #pragma unroll
            for (int g = 0; g < 4; ++g)
                if (!(SKIPF && g == 1)) bqc[g] = bqn[g];
        } else if (PF) {
            #pragma unroll
            for (int g = 0; g < 4; ++g)
                if (!(NSKIPF && g == 1)) bqc[g] = bqn[g];
        }
    }
}

__global__ __launch_bounds__(512) void lstm_main(
    const float* __restrict__ x, const _Float16* __restrict__ Wp_in,
    const float* __restrict__ bias0f_in, const float* __restrict__ bias1f_in,
    const float* __restrict__ mu_g2_in, const float* __restrict__ fc_w_in,
    const float* __restrict__ fc_b_in, float* __restrict__ out)
{
    // LDS 49152 B:
    //  [0, 16384)       H1s   (swizzled [64][256B])
    //  [16384, 32768)   H2s   -- ALSO hosts A0 (64 x 72 halfs = 9216 B):
    //                      A0 dead at S1-barrier (lgkmcnt(0) drains its
    //                      ds_reads); H2s first written in epi2 after it.
    //  [32768, 49152)   H11s
    __shared__ __align__(16) char smem[49152];
    char* H1s  = smem;
    char* H2s  = smem + 16384;
    char* H11s = smem + 32768;
    _Float16* A0 = (_Float16*)(smem + 16384);    // alias of H2s region

    const int t = threadIdx.x;
    const int w = t >> 6, lane = t & 63, c = lane & 15, q = lane >> 4;
    const int wg = blockIdx.x;                   // 1024 wgs x 64 rows
    const int b = wg >> 4;                       // 16 wgs (1024 rows) per batch
    const int bq_idx = w * 4 + q;                // float4 index of (w,q) slice

    // ---- prefetch S1 kc=0 weights {i,g,o} with maximum lead ---------------
    half8 bqc[4];
    load_bq<true>(bqc, Wp_in + WP_WIH0, 2, 0, w, lane);

    // ---- preamble: stage x tile into A0 (coalesced); init out rows --------
    {
        const float* xp = x + (size_t)wg * 4096 + t * 8;
        float4 u0 = ((const float4*)xp)[0];
        float4 u1 = ((const float4*)xp)[1];
        half8 hv;
        hv[0] = (_Float16)u0.x; hv[1] = (_Float16)u0.y;
        hv[2] = (_Float16)u0.z; hv[3] = (_Float16)u0.w;
        hv[4] = (_Float16)u1.x; hv[5] = (_Float16)u1.y;
        hv[6] = (_Float16)u1.z; hv[7] = (_Float16)u1.w;
        *(half8*)(A0 + (t >> 3) * 72 + (t & 7) * 8) = hv;
        if (t < 64) out[(size_t)wg * 64 + t] = fc_b_in[0];
    }
    lds_barrier();   // A0 visible (lgkm); weight prefetch still in flight

    f32x4 acc[4][4];
    float cc[4][4];

    // ---- S1: layer0 step1 (A from A0; bias0 as C; gates {i,g,o}) ----------
    {
        f32x4 bv[4];
        {
            const float* bias0f = bias0f_in; asm volatile("" : "+s"(bias0f));
            #pragma unroll
            for (int g = 0; g < 4; ++g)
                if (g != 1) bv[g] = ((const f32x4*)bias0f)[g * 32 + bq_idx];
        }
        gemm_pf<2, 0, true, true, true, false>(
            Wp_in + WP_WIH0, (const char*)A0,
            Wp_in + WP_WHH0, 4, bqc, bv, w, lane, acc);
    }
    // epi1: c1 = sig(i)tanh(g) [fused]; h1 = sig(o)tanh(c1) [fused]
    #pragma unroll
    for (int mt = 0; mt < 4; ++mt) {
        half4_t hv;
        #pragma unroll
        for (int r = 0; r < 4; ++r) {
            float c1 = sigtanh(acc[mt][0][r], acc[mt][2][r]);
            cc[mt][r] = c1;
            hv[r] = (_Float16)sigtanh(acc[mt][3][r], c1 * L2E2);
        }
        *(half4_t*)(H1s + swz(mt * 16 + c, w * 32 + q * 8)) = hv;
    }
    lds_barrier();   // [S1-barrier] H1s ready; A0 dead; Whh0 kc=0 in flight

    // ---- S2: layer0 step2 (A from H1s; mu_g2 as C; all gates) -------------
    // Tail prefetches Wih1 kc=0 for S3 (gates {i,g,o}).
    {
        f32x4 bv[4];
        {
            const float* mu_g2b = mu_g2_in + b * 512; asm volatile("" : "+s"(mu_g2b));
            #pragma unroll
            for (int g = 0; g < 4; ++g)
                bv[g] = ((const f32x4*)mu_g2b)[g * 32 + bq_idx];
        }
        gemm_pf<4, 1, true, true, false, true>(
            Wp_in + WP_WHH0, H1s,
            Wp_in + WP_WIH1, 4, bqc, bv, w, lane, acc);
    }
    // epi2: c2 = sig(f)*c1 + sig(i)tanh(g) [fused]; h2 = sig(o)tanh(c2) [fused]
    #pragma unroll
    for (int mt = 0; mt < 4; ++mt) {
        half4_t hv;
        #pragma unroll
        for (int r = 0; r < 4; ++r) {
            float c2 = sig2(acc[mt][1][r]) * cc[mt][r]
                     + sigtanh(acc[mt][0][r], acc[mt][2][r]);
            hv[r] = (_Float16)sigtanh(acc[mt][3][r], c2 * L2E2);
        }
        *(half4_t*)(H2s + swz(mt * 16 + c, w * 32 + q * 8)) = hv;
    }

    // ---- S3: layer1 step1 (A from H1s; bias1 as C; gates {i,g,o}) ---------
    // Tail prefetches Wih1 kc=0 for S4a (all gates; L2-hot).
    {
        f32x4 bv[4];
        {
            const float* bias1f = bias1f_in; asm volatile("" : "+s"(bias1f));
            #pragma unroll
            for (int g = 0; g < 4; ++g)
                if (g != 1) bv[g] = ((const f32x4*)bias1f)[g * 32 + bq_idx];
        }
        gemm_pf<4, 1, true, true, true, false>(
            Wp_in + WP_WIH1, H1s,
            Wp_in + WP_WIH1, 4, bqc, bv, w, lane, acc);
    }
    // epi3: h11 -> H11s, cc := layer-1 c1 (both fused)
    #pragma unroll
    for (int mt = 0; mt < 4; ++mt) {
        half4_t hv;
        #pragma unroll
        for (int r = 0; r < 4; ++r) {
            float c1 = sigtanh(acc[mt][0][r], acc[mt][2][r]);
            cc[mt][r] = c1;
            hv[r] = (_Float16)sigtanh(acc[mt][3][r], c1 * L2E2);
        }
        *(half4_t*)(H11s + swz(mt * 16 + c, w * 32 + q * 8)) = hv;
    }
    lds_barrier();   // [S3-barrier] H2s + H11s ready; Wih1 kc=0 in flight

    // ---- S4: layer1 step2 (Wih1@H2s + Whh1@H11s; bias1 as C; all gates) ---
    {
        f32x4 bv[4];
        {
            const float* bias1f = bias1f_in; asm volatile("" : "+s"(bias1f));
            #pragma unroll
            for (int g = 0; g < 4; ++g)
                bv[g] = ((const f32x4*)bias1f)[g * 32 + bq_idx];
        }
        gemm_pf<4, 1, true, true, false, false>(
            Wp_in + WP_WIH1, H2s,
            Wp_in + WP_WHH1, 4, bqc, bv, w, lane, acc);
    }
    gemm_pf<4, 1, false, false, false, false>(
        Wp_in + WP_WHH1, H11s,
        nullptr, 0, bqc, nullptr, w, lane, acc);

    // epilogue: h2_1 -> relu -> dot fc_w; partials straight to L2 atomics
    // (out pre-inited with fc_b in preamble; only this wg touches these 64
    //  rows; the store retires during the intervening vmcnt traffic).
    {
        const float* fc_w = fc_w_in; asm volatile("" : "+s"(fc_w));
        f32x4 fwv = ((const f32x4*)fc_w)[bq_idx];
        #pragma unroll
        for (int mt = 0; mt < 4; ++mt) {
            float v = 0.0f;
            #pragma unroll
            for (int r = 0; r < 4; ++r) {
                float c2 = sig2(acc[mt][1][r]) * cc[mt][r]
                         + sigtanh(acc[mt][0][r], acc[mt][2][r]);
                float h  = sigtanh(acc[mt][3][r], c2 * L2E2);
                v = fmaf(fmaxf(h, 0.0f), fwv[r], v);
            }
            v += __shfl_xor(v, 16);
            v += __shfl_xor(v, 32);
            if (lane < 16)
                atomicAdd(out + (size_t)wg * 64 + mt * 16 + lane, v);
        }
    }
}

extern "C" void kernel_launch(void* const* d_in, const int* in_sizes, int n_in,
                              void* d_out, int out_size, void* d_ws, size_t ws_size,
                              hipStream_t stream)
{
    const float* x    = (const float*)d_in[0];
    const float* mu   = (const float*)d_in[1];
    const float* Wih0 = (const float*)d_in[2];
    const float* Whh0 = (const float*)d_in[3];
    const float* bih0 = (const float*)d_in[4];
    const float* bhh0 = (const float*)d_in[5];
    const float* Wih1 = (const float*)d_in[6];
    const float* Whh1 = (const float*)d_in[7];
    const float* bih1 = (const float*)d_in[8];
    const float* bhh1 = (const float*)d_in[9];
    const float* fcw  = (const float*)d_in[10];
    const float* fcb  = (const float*)d_in[11];
    float* out = (float*)d_out;

    _Float16* Wp  = (_Float16*)d_ws;
    float* bias0f = (float*)((char*)d_ws + WS_BIAS0);
    float* bias1f = (float*)((char*)d_ws + WS_BIAS1);
    float* mu_g2  = (float*)((char*)d_ws + WS_MUG2);

    hipLaunchKernelGGL(prep_kernel, dim3(241), dim3(256), 0, stream,
                       Wih0, Whh0, Wih1, Whh1, bih0, bhh0, bih1, bhh1, mu,
                       Wp, bias0f, bias1f, mu_g2);
    hipLaunchKernelGGL(lstm_main, dim3(1024), dim3(512), 0, stream,
                       x, Wp, bias0f, bias1f, mu_g2, fcw, fcb, out);
}